// Round 9
// baseline (215.309 us; speedup 1.0000x reference)
//
#include <hip/hip_runtime.h>
#include <stdint.h>

#define DD 768
#define HN 8
#define LL 4096
#define BB 32
#define ROWS 64                 // rows per chunk (one block, both waves see all rows)
#define NBLK (BB * LL / ROWS)   // 2048 blocks x 128 threads
#define DEPTH 4                 // ring slots per wave (12 KB/wave, 24 KB/block)
#define PSTR 772                // per-(block,head) partial: S[768], se at [768]

#define GLOBAL_AS __attribute__((address_space(1)))
#define LDS_AS    __attribute__((address_space(3)))

// ---- DPP wave64 sum: 6 rounds, VALU-only ----
#define DPP_STEP(x, ctrl, rmask, bc)                                           \
  x += __int_as_float(__builtin_amdgcn_update_dpp(                             \
      0, __float_as_int(x), (ctrl), (rmask), 0xf, (bc)))

__device__ __forceinline__ void wave_sum4(float& a, float& b, float& c, float& d) {
  DPP_STEP(a, 0x111, 0xf, true);  DPP_STEP(b, 0x111, 0xf, true);
  DPP_STEP(c, 0x111, 0xf, true);  DPP_STEP(d, 0x111, 0xf, true);
  DPP_STEP(a, 0x112, 0xf, true);  DPP_STEP(b, 0x112, 0xf, true);
  DPP_STEP(c, 0x112, 0xf, true);  DPP_STEP(d, 0x112, 0xf, true);
  DPP_STEP(a, 0x114, 0xf, true);  DPP_STEP(b, 0x114, 0xf, true);
  DPP_STEP(c, 0x114, 0xf, true);  DPP_STEP(d, 0x114, 0xf, true);
  DPP_STEP(a, 0x118, 0xf, true);  DPP_STEP(b, 0x118, 0xf, true);
  DPP_STEP(c, 0x118, 0xf, true);  DPP_STEP(d, 0x118, 0xf, true);
  DPP_STEP(a, 0x142, 0xa, false); DPP_STEP(b, 0x142, 0xa, false);
  DPP_STEP(c, 0x142, 0xa, false); DPP_STEP(d, 0x142, 0xa, false);
  DPP_STEP(a, 0x143, 0xc, false); DPP_STEP(b, 0x143, 0xc, false);
  DPP_STEP(c, 0x143, 0xc, false); DPP_STEP(d, 0x143, 0xc, false);
  a = __int_as_float(__builtin_amdgcn_readlane(__float_as_int(a), 63));
  b = __int_as_float(__builtin_amdgcn_readlane(__float_as_int(b), 63));
  c = __int_as_float(__builtin_amdgcn_readlane(__float_as_int(c), 63));
  d = __int_as_float(__builtin_amdgcn_readlane(__float_as_int(d), 63));
}

__device__ __forceinline__ void wave_sum2(float& a, float& b) {
  DPP_STEP(a, 0x111, 0xf, true);  DPP_STEP(b, 0x111, 0xf, true);
  DPP_STEP(a, 0x112, 0xf, true);  DPP_STEP(b, 0x112, 0xf, true);
  DPP_STEP(a, 0x114, 0xf, true);  DPP_STEP(b, 0x114, 0xf, true);
  DPP_STEP(a, 0x118, 0xf, true);  DPP_STEP(b, 0x118, 0xf, true);
  DPP_STEP(a, 0x142, 0xa, false); DPP_STEP(b, 0x142, 0xa, false);
  DPP_STEP(a, 0x143, 0xc, false); DPP_STEP(b, 0x143, 0xc, false);
  a = __int_as_float(__builtin_amdgcn_readlane(__float_as_int(a), 63));
  b = __int_as_float(__builtin_amdgcn_readlane(__float_as_int(b), 63));
}

// ---------------- kernel 0: centered qk0[h][d] = G[d] - mean_d(G)  (R7-proven)
__global__ __launch_bounds__(768) void k_qk(const float* __restrict__ wkv,
                                            const float* __restrict__ query,
                                            const float* __restrict__ gamma1,
                                            float* __restrict__ qk) {
  int h = blockIdx.x;
  int d = threadIdx.x;
  const float* wbase = wkv + (size_t)h * 96 * DD + d;
  const float* qb = query + h * 96;
  float acc = 0.f;
  #pragma unroll 8
  for (int i = 0; i < 96; ++i) acc = fmaf(qb[i], wbase[(size_t)i * DD], acc);
  acc *= 0.10206207261596577f * gamma1[d];   // 96^-0.5 * gamma1
  __shared__ float wsum[12];
  __shared__ float meanv;
  float v = acc;
  #pragma unroll
  for (int off = 1; off < 64; off <<= 1) v += __shfl_xor(v, off, 64);
  if ((d & 63) == 0) wsum[d >> 6] = v;
  __syncthreads();
  if (d == 0) {
    float s = 0.f;
    #pragma unroll
    for (int i = 0; i < 12; ++i) s += wsum[i];
    meanv = s * (1.f / 768.f);
  }
  __syncthreads();
  qk[h * DD + d] = acc - meanv;
}

// ---------------- kernel 1: two INDEPENDENT 1-wave pipelines per block.
// Wave w owns heads {4w..4w+3}; each wave has a private LDS ring and stages all
// rows itself (twin wave's DMA hits L1/L2 on the same CU). Zero barriers.
__global__ __launch_bounds__(128, 3) void k_main(
    const float* __restrict__ x, const float* __restrict__ qk,
    float* __restrict__ part) {
  const int lane = threadIdx.x & 63;
  const int wave = threadIdx.x >> 6;
  const int h0 = wave * 4;

  __shared__ float lds[2][DEPTH][DD];       // 24 KB, partitioned by wave
  float* ring = &lds[wave][0][0];

  // q fragments for 4 owned heads (element j*256 + lane*4 + c), pre-centered
  float4 q[4][3];
  #pragma unroll
  for (int h = 0; h < 4; ++h)
    #pragma unroll
    for (int j = 0; j < 3; ++j)
      q[h][j] = *reinterpret_cast<const float4*>(qk + (h0 + h) * DD + j * 256 + lane * 4);
  asm volatile("s_waitcnt vmcnt(0)" ::: "memory");  // q landed; vmcnt tracks stages only

  float4 S[4][3];
  float se[4], ch[4];
  #pragma unroll
  for (int h = 0; h < 4; ++h) {
    se[h] = 0.f; ch[h] = 0.f;
    #pragma unroll
    for (int j = 0; j < 3; ++j) S[h][j] = make_float4(0.f, 0.f, 0.f, 0.f);
  }

  const float* gbase = x + (size_t)blockIdx.x * ROWS * DD;

  // stage row R into this wave's ring slot R&3: 3x 16B DMA (3 vmcnt events)
  #define STAGE(R)                                                             \
    {                                                                          \
      const float* gt = gbase + (size_t)(R) * DD;                              \
      float* db = ring + ((R) & (DEPTH - 1)) * DD;                             \
      _Pragma("unroll")                                                        \
      for (int i = 0; i < 3; ++i)                                              \
        __builtin_amdgcn_global_load_lds(                                      \
            (const GLOBAL_AS uint32_t*)(gt + i * 256 + lane * 4),              \
            (LDS_AS uint32_t*)(db + i * 256), 16, 0, 0);                       \
    }

  #define COMPUTE(RR)                                                          \
    {                                                                          \
      const float* row = ring + ((RR) & (DEPTH - 1)) * DD;                     \
      float4 c0 = *reinterpret_cast<const float4*>(row + lane * 4);            \
      float4 c1 = *reinterpret_cast<const float4*>(row + 256 + lane * 4);      \
      float4 c2 = *reinterpret_cast<const float4*>(row + 512 + lane * 4);      \
      float s1 = 0.f, s2 = 0.f;                                                \
      float dt[4] = {0.f, 0.f, 0.f, 0.f};                                      \
      ACC4(c0, 0) ACC4(c1, 1) ACC4(c2, 2)                                      \
      wave_sum4(s1, s2, dt[0], dt[1]);                                         \
      wave_sum2(dt[2], dt[3]);                                                 \
      float mu   = s1 * (1.f / 768.f);                                         \
      float var  = fmaf(-mu, mu, s2 * (1.f / 768.f));                          \
      float rstd = rsqrtf(var + 1e-5f);                                        \
      float sh   = -mu * rstd;                                                 \
      float pe   = rstd * 1.44269504f;                                         \
      _Pragma("unroll")                                                        \
      for (int h = 0; h < 4; ++h) {                                            \
        float p = exp2f(dt[h] * pe);                                           \
        se[h] += p;                                                            \
        ch[h] = fmaf(p, sh, ch[h]);                                            \
        float a = p * rstd;                                                    \
        S[h][0].x = fmaf(a, c0.x, S[h][0].x);                                  \
        S[h][0].y = fmaf(a, c0.y, S[h][0].y);                                  \
        S[h][0].z = fmaf(a, c0.z, S[h][0].z);                                  \
        S[h][0].w = fmaf(a, c0.w, S[h][0].w);                                  \
        S[h][1].x = fmaf(a, c1.x, S[h][1].x);                                  \
        S[h][1].y = fmaf(a, c1.y, S[h][1].y);                                  \
        S[h][1].z = fmaf(a, c1.z, S[h][1].z);                                  \
        S[h][1].w = fmaf(a, c1.w, S[h][1].w);                                  \
        S[h][2].x = fmaf(a, c2.x, S[h][2].x);                                  \
        S[h][2].y = fmaf(a, c2.y, S[h][2].y);                                  \
        S[h][2].z = fmaf(a, c2.z, S[h][2].z);                                  \
        S[h][2].w = fmaf(a, c2.w, S[h][2].w);                                  \
      }                                                                        \
    }

#define ACC4(cv, J)                                                            \
      s1 += cv.x + cv.y + cv.z + cv.w;                                         \
      s2 = fmaf(cv.x, cv.x, s2); s2 = fmaf(cv.y, cv.y, s2);                    \
      s2 = fmaf(cv.z, cv.z, s2); s2 = fmaf(cv.w, cv.w, s2);                    \
      _Pragma("unroll")                                                        \
      for (int h = 0; h < 4; ++h) {                                            \
        dt[h] = fmaf(cv.x, q[h][J].x, dt[h]);                                  \
        dt[h] = fmaf(cv.y, q[h][J].y, dt[h]);                                  \
        dt[h] = fmaf(cv.z, q[h][J].z, dt[h]);                                  \
        dt[h] = fmaf(cv.w, q[h][J].w, dt[h]);                                  \
      }

  // prologue: 3 rows in flight (9 loads); wave-private pipeline, no barriers
  STAGE(0) STAGE(1) STAGE(2)

  #pragma unroll 1
  for (int r = 0; r <= ROWS - 4; ++r) {
    STAGE(r + 3)                                       // 12 outstanding
    asm volatile("s_waitcnt vmcnt(9)" ::: "memory");   // row r landed
    COMPUTE(r)
  }
  asm volatile("s_waitcnt vmcnt(6)" ::: "memory");
  COMPUTE(ROWS - 3)
  asm volatile("s_waitcnt vmcnt(3)" ::: "memory");
  COMPUTE(ROWS - 2)
  asm volatile("s_waitcnt vmcnt(0)" ::: "memory");
  COMPUTE(ROWS - 1)

  #undef ACC4
  #undef COMPUTE
  #undef STAGE

  // epilogue: wave-private partial write (4 heads)
  float* pb = part + (size_t)blockIdx.x * (HN * PSTR) + (size_t)h0 * PSTR;
  #pragma unroll
  for (int h = 0; h < 4; ++h) {
    #pragma unroll
    for (int j = 0; j < 3; ++j) {
      float4 v = S[h][j];
      v.x += ch[h]; v.y += ch[h]; v.z += ch[h]; v.w += ch[h];
      *reinterpret_cast<float4*>(pb + h * PSTR + j * 256 + lane * 4) = v;
    }
  }
  if (lane == 0) {
    #pragma unroll
    for (int h = 0; h < 4; ++h) pb[h * PSTR + 768] = se[h];
  }
}

// ---------------- kernel 2a: combine 64 chunk partials -> xbar[b][h][768]
__global__ __launch_bounds__(256) void k_red(const float* __restrict__ part,
                                             const float* __restrict__ gamma1,
                                             const float* __restrict__ beta1,
                                             float* __restrict__ xbar) {
  int b = blockIdx.x >> 3;
  int h = blockIdx.x & 7;
  int t = threadIdx.x;
  const int CPB = LL / ROWS;   // 64 chunks per batch
  const float* pb = part + ((size_t)b * CPB * HN + h) * PSTR;
  float se = 0.f, a0 = 0.f, a1 = 0.f, a2 = 0.f;
  for (int i = 0; i < CPB; ++i) {
    const float* P = pb + (size_t)i * HN * PSTR;
    se += P[768];
    a0 += P[t];
    a1 += P[t + 256];
    a2 += P[t + 512];
  }
  float inv = 1.f / se;
  size_t ob = ((size_t)b * HN + h) * DD;
  xbar[ob + t]       = fmaf(gamma1[t],       a0 * inv, beta1[t]);
  xbar[ob + t + 256] = fmaf(gamma1[t + 256], a1 * inv, beta1[t + 256]);
  xbar[ob + t + 512] = fmaf(gamma1[t + 512], a2 * inv, beta1[t + 512]);
}

// ---------------- kernel 2b: V-projection (96 blocks: 32 b x 3 g-chunks)
__global__ __launch_bounds__(256) void k_proj(
    const float* __restrict__ xbar, const float* __restrict__ wkv,
    float* __restrict__ outp) {
  int b  = blockIdx.x / 3;
  int gc = blockIdx.x % 3;
  int t  = threadIdx.x;
  __shared__ float xb[HN * DD];
  #pragma unroll
  for (int k = 0; k < 24; ++k) xb[k * 256 + t] = xbar[(size_t)b * HN * DD + k * 256 + t];
  __syncthreads();

  int g = gc * 256 + t;
  int h = g / 96;
  const float4* wrow = reinterpret_cast<const float4*>(wkv + (size_t)(DD + g) * DD);
  const float* xh = xb + h * DD;
  float acc = 0.f;
  #pragma unroll 4
  for (int e = 0; e < 192; ++e) {
    float4 w = wrow[e];
    acc = fmaf(w.x, xh[e * 4 + 0], acc);
    acc = fmaf(w.y, xh[e * 4 + 1], acc);
    acc = fmaf(w.z, xh[e * 4 + 2], acc);
    acc = fmaf(w.w, xh[e * 4 + 3], acc);
  }
  outp[(size_t)b * DD + g] = acc;
}

// ---------------- kernel 2c: final LN over 768
__global__ __launch_bounds__(768) void k_ln2(
    const float* __restrict__ outp, const float* __restrict__ gamma2,
    const float* __restrict__ beta2, float* __restrict__ out) {
  int b = blockIdx.x;
  int t = threadIdx.x;
  __shared__ float rs1[12], rs2[12];
  __shared__ float smu, srstd;
  float o = outp[(size_t)b * DD + t];
  float v1 = o, v2 = o * o;
  #pragma unroll
  for (int off = 1; off < 64; off <<= 1) {
    v1 += __shfl_xor(v1, off, 64);
    v2 += __shfl_xor(v2, off, 64);
  }
  int wv = t >> 6, ln = t & 63;
  if (ln == 0) { rs1[wv] = v1; rs2[wv] = v2; }
  __syncthreads();
  if (t == 0) {
    float s1 = 0.f, s2 = 0.f;
    #pragma unroll
    for (int w = 0; w < 12; ++w) { s1 += rs1[w]; s2 += rs2[w]; }
    float mu = s1 * (1.f / 768.f);
    float var = fmaf(-mu, mu, s2 * (1.f / 768.f));
    smu = mu;
    srstd = rsqrtf(var + 1e-5f);
  }
  __syncthreads();
  out[(size_t)b * DD + t] = fmaf((o - smu) * srstd, gamma2[t], beta2[t]);
}

extern "C" void kernel_launch(void* const* d_in, const int* in_sizes, int n_in,
                              void* d_out, int out_size, void* d_ws, size_t ws_size,
                              hipStream_t stream) {
  const float* x     = (const float*)d_in[0];
  const float* wkv   = (const float*)d_in[1];
  const float* query = (const float*)d_in[2];
  const float* g1    = (const float*)d_in[3];
  const float* b1    = (const float*)d_in[4];
  const float* g2    = (const float*)d_in[5];
  const float* b2    = (const float*)d_in[6];
  float* out = (float*)d_out;
  float* ws  = (float*)d_ws;

  float* qk   = ws;                                    // 6144 floats (pad 8192)
  float* part = ws + 8192;                             // NBLK*HN*PSTR (~50.6 MB)
  float* xbar = part + (size_t)NBLK * HN * PSTR;       // BB*HN*DD
  float* outp = xbar + (size_t)BB * HN * DD;           // BB*DD

  k_qk  <<<HN,      768, 0, stream>>>(wkv, query, g1, qk);
  k_main<<<NBLK,    128, 0, stream>>>(x, qk, part);
  k_red <<<BB * HN, 256, 0, stream>>>(part, g1, b1, xbar);
  k_proj<<<BB * 3,  256, 0, stream>>>(xbar, wkv, outp);
  k_ln2 <<<BB,      768, 0, stream>>>(outp, g2, b2, out);
}

// Round 10
// 188.627 us; speedup vs baseline: 1.1415x; 1.1415x over previous
//
#include <hip/hip_runtime.h>
#include <stdint.h>

#define DD 768
#define HN 8
#define LL 4096
#define BB 32
#define ROWS 64                 // rows per 1-wave block
#define NBLK (BB * LL / ROWS)   // 2048 blocks = 8/CU x 256 CU
#define DEPTH 6                 // ring slots (18 KB) -> 5-row-deep prefetch
#define PSTR 772                // per-(block,head) partial: S[768], se at [768]

#define GLOBAL_AS __attribute__((address_space(1)))
#define LDS_AS    __attribute__((address_space(3)))

// ---- DPP wave64 sum: 6 rounds, VALU-only ----
#define DPP_STEP(x, ctrl, rmask, bc)                                           \
  x += __int_as_float(__builtin_amdgcn_update_dpp(                             \
      0, __float_as_int(x), (ctrl), (rmask), 0xf, (bc)))

__device__ __forceinline__ void wave_sum4(float& a, float& b, float& c, float& d) {
  DPP_STEP(a, 0x111, 0xf, true);  DPP_STEP(b, 0x111, 0xf, true);
  DPP_STEP(c, 0x111, 0xf, true);  DPP_STEP(d, 0x111, 0xf, true);
  DPP_STEP(a, 0x112, 0xf, true);  DPP_STEP(b, 0x112, 0xf, true);
  DPP_STEP(c, 0x112, 0xf, true);  DPP_STEP(d, 0x112, 0xf, true);
  DPP_STEP(a, 0x114, 0xf, true);  DPP_STEP(b, 0x114, 0xf, true);
  DPP_STEP(c, 0x114, 0xf, true);  DPP_STEP(d, 0x114, 0xf, true);
  DPP_STEP(a, 0x118, 0xf, true);  DPP_STEP(b, 0x118, 0xf, true);
  DPP_STEP(c, 0x118, 0xf, true);  DPP_STEP(d, 0x118, 0xf, true);
  DPP_STEP(a, 0x142, 0xa, false); DPP_STEP(b, 0x142, 0xa, false);
  DPP_STEP(c, 0x142, 0xa, false); DPP_STEP(d, 0x142, 0xa, false);
  DPP_STEP(a, 0x143, 0xc, false); DPP_STEP(b, 0x143, 0xc, false);
  DPP_STEP(c, 0x143, 0xc, false); DPP_STEP(d, 0x143, 0xc, false);
  a = __int_as_float(__builtin_amdgcn_readlane(__float_as_int(a), 63));
  b = __int_as_float(__builtin_amdgcn_readlane(__float_as_int(b), 63));
  c = __int_as_float(__builtin_amdgcn_readlane(__float_as_int(c), 63));
  d = __int_as_float(__builtin_amdgcn_readlane(__float_as_int(d), 63));
}

__device__ __forceinline__ void wave_sum2(float& a, float& b) {
  DPP_STEP(a, 0x111, 0xf, true);  DPP_STEP(b, 0x111, 0xf, true);
  DPP_STEP(a, 0x112, 0xf, true);  DPP_STEP(b, 0x112, 0xf, true);
  DPP_STEP(a, 0x114, 0xf, true);  DPP_STEP(b, 0x114, 0xf, true);
  DPP_STEP(a, 0x118, 0xf, true);  DPP_STEP(b, 0x118, 0xf, true);
  DPP_STEP(a, 0x142, 0xa, false); DPP_STEP(b, 0x142, 0xa, false);
  DPP_STEP(a, 0x143, 0xc, false); DPP_STEP(b, 0x143, 0xc, false);
  a = __int_as_float(__builtin_amdgcn_readlane(__float_as_int(a), 63));
  b = __int_as_float(__builtin_amdgcn_readlane(__float_as_int(b), 63));
}

// ---------------- kernel 0: RAW qk[h][d] = gamma1[d]*scale*sum_i q[h*96+i]*w[h*96+i][d]
// (24 blocks for CU spread; centering folded into k_main)
__global__ __launch_bounds__(256) void k_qk(const float* __restrict__ wkv,
                                            const float* __restrict__ query,
                                            const float* __restrict__ gamma1,
                                            float* __restrict__ qkraw) {
  int h = blockIdx.x / 3;
  int d = (blockIdx.x % 3) * 256 + threadIdx.x;
  const float* wbase = wkv + (size_t)h * 96 * DD + d;
  const float* qb = query + h * 96;
  float acc = 0.f;
  #pragma unroll 8
  for (int i = 0; i < 96; ++i) acc = fmaf(qb[i], wbase[(size_t)i * DD], acc);
  qkraw[h * DD + d] = acc * 0.10206207261596577f * gamma1[d];
}

// ---------------- kernel 1: 1-wave blocks, 8 heads/wave, barrier-free 6-deep ring
__global__ __launch_bounds__(64, 2) void k_main(
    const float* __restrict__ x, const float* __restrict__ qkraw,
    float* __restrict__ part) {
  const int lane = threadIdx.x;          // 0..63
  __shared__ float lds[DEPTH][DD];       // private ring, 18 KB
  float* ring = &lds[0][0];

  // q fragments for all 8 heads (element j*256 + lane*4 + c)
  float4 q[HN][3];
  #pragma unroll
  for (int h = 0; h < HN; ++h)
    #pragma unroll
    for (int j = 0; j < 3; ++j)
      q[h][j] = *reinterpret_cast<const float4*>(qkraw + h * DD + j * 256 + lane * 4);
  asm volatile("s_waitcnt vmcnt(0)" ::: "memory");  // q landed; vmcnt tracks stages only

  // center each head's qk vector (softmax-shift-exact, same math as before)
  {
    float m[HN];
    #pragma unroll
    for (int h = 0; h < HN; ++h) {
      float s = 0.f;
      #pragma unroll
      for (int j = 0; j < 3; ++j)
        s += q[h][j].x + q[h][j].y + q[h][j].z + q[h][j].w;
      m[h] = s;
    }
    wave_sum4(m[0], m[1], m[2], m[3]);
    wave_sum4(m[4], m[5], m[6], m[7]);
    #pragma unroll
    for (int h = 0; h < HN; ++h) {
      float mv = m[h] * (1.f / 768.f);
      #pragma unroll
      for (int j = 0; j < 3; ++j) {
        q[h][j].x -= mv; q[h][j].y -= mv; q[h][j].z -= mv; q[h][j].w -= mv;
      }
    }
  }

  float4 S[HN][3];
  float se[HN], ch[HN];
  #pragma unroll
  for (int h = 0; h < HN; ++h) {
    se[h] = 0.f; ch[h] = 0.f;
    #pragma unroll
    for (int j = 0; j < 3; ++j) S[h][j] = make_float4(0.f, 0.f, 0.f, 0.f);
  }

  const float* gbase = x + (size_t)blockIdx.x * ROWS * DD;

  // stage row R into ring slot SLOT: 3x 16B DMA (3 vmcnt events)
  #define STAGE(R, SLOT)                                                       \
    {                                                                          \
      const float* gt = gbase + (size_t)(R) * DD;                              \
      float* db = ring + (SLOT) * DD;                                          \
      _Pragma("unroll")                                                        \
      for (int i = 0; i < 3; ++i)                                              \
        __builtin_amdgcn_global_load_lds(                                      \
            (const GLOBAL_AS uint32_t*)(gt + i * 256 + lane * 4),              \
            (LDS_AS uint32_t*)(db + i * 256), 16, 0, 0);                       \
    }

  #define COMPUTE(SLOT)                                                        \
    {                                                                          \
      const float* row = ring + (SLOT) * DD;                                   \
      float4 c0 = *reinterpret_cast<const float4*>(row + lane * 4);            \
      float4 c1 = *reinterpret_cast<const float4*>(row + 256 + lane * 4);      \
      float4 c2 = *reinterpret_cast<const float4*>(row + 512 + lane * 4);      \
      float s1 = 0.f, s2 = 0.f;                                                \
      float dt[HN];                                                            \
      _Pragma("unroll") for (int h = 0; h < HN; ++h) dt[h] = 0.f;              \
      ACC4(c0, 0) ACC4(c1, 1) ACC4(c2, 2)                                      \
      wave_sum4(s1, s2, dt[0], dt[1]);                                         \
      wave_sum4(dt[2], dt[3], dt[4], dt[5]);                                   \
      wave_sum2(dt[6], dt[7]);                                                 \
      float mu   = s1 * (1.f / 768.f);                                         \
      float var  = fmaf(-mu, mu, s2 * (1.f / 768.f));                          \
      float rstd = rsqrtf(var + 1e-5f);                                        \
      float sh   = -mu * rstd;                                                 \
      float pe   = rstd * 1.44269504f;                                         \
      _Pragma("unroll")                                                        \
      for (int h = 0; h < HN; ++h) {                                           \
        float p = exp2f(dt[h] * pe);                                           \
        se[h] += p;                                                            \
        ch[h] = fmaf(p, sh, ch[h]);                                            \
        float a = p * rstd;                                                    \
        S[h][0].x = fmaf(a, c0.x, S[h][0].x);                                  \
        S[h][0].y = fmaf(a, c0.y, S[h][0].y);                                  \
        S[h][0].z = fmaf(a, c0.z, S[h][0].z);                                  \
        S[h][0].w = fmaf(a, c0.w, S[h][0].w);                                  \
        S[h][1].x = fmaf(a, c1.x, S[h][1].x);                                  \
        S[h][1].y = fmaf(a, c1.y, S[h][1].y);                                  \
        S[h][1].z = fmaf(a, c1.z, S[h][1].z);                                  \
        S[h][1].w = fmaf(a, c1.w, S[h][1].w);                                  \
        S[h][2].x = fmaf(a, c2.x, S[h][2].x);                                  \
        S[h][2].y = fmaf(a, c2.y, S[h][2].y);                                  \
        S[h][2].z = fmaf(a, c2.z, S[h][2].z);                                  \
        S[h][2].w = fmaf(a, c2.w, S[h][2].w);                                  \
      }                                                                        \
    }

#define ACC4(cv, J)                                                            \
      s1 += cv.x + cv.y + cv.z + cv.w;                                         \
      s2 = fmaf(cv.x, cv.x, s2); s2 = fmaf(cv.y, cv.y, s2);                    \
      s2 = fmaf(cv.z, cv.z, s2); s2 = fmaf(cv.w, cv.w, s2);                    \
      _Pragma("unroll")                                                        \
      for (int h = 0; h < HN; ++h) {                                           \
        dt[h] = fmaf(cv.x, q[h][J].x, dt[h]);                                  \
        dt[h] = fmaf(cv.y, q[h][J].y, dt[h]);                                  \
        dt[h] = fmaf(cv.z, q[h][J].z, dt[h]);                                  \
        dt[h] = fmaf(cv.w, q[h][J].w, dt[h]);                                  \
      }

  // prologue: 5 rows in flight (15 loads) into slots 0..4
  STAGE(0, 0) STAGE(1, 1) STAGE(2, 2) STAGE(3, 3) STAGE(4, 4)

  int sIn = 5, sCur = 0;
  #pragma unroll 1
  for (int r = 0; r <= ROWS - 6; ++r) {
    STAGE(r + 5, sIn)                                  // 18 outstanding
    sIn = (sIn == DEPTH - 1) ? 0 : sIn + 1;
    asm volatile("s_waitcnt vmcnt(15)" ::: "memory");  // row r landed
    COMPUTE(sCur)
    sCur = (sCur == DEPTH - 1) ? 0 : sCur + 1;
  }
  asm volatile("s_waitcnt vmcnt(12)" ::: "memory");
  COMPUTE(sCur) sCur = (sCur == DEPTH - 1) ? 0 : sCur + 1;
  asm volatile("s_waitcnt vmcnt(9)" ::: "memory");
  COMPUTE(sCur) sCur = (sCur == DEPTH - 1) ? 0 : sCur + 1;
  asm volatile("s_waitcnt vmcnt(6)" ::: "memory");
  COMPUTE(sCur) sCur = (sCur == DEPTH - 1) ? 0 : sCur + 1;
  asm volatile("s_waitcnt vmcnt(3)" ::: "memory");
  COMPUTE(sCur) sCur = (sCur == DEPTH - 1) ? 0 : sCur + 1;
  asm volatile("s_waitcnt vmcnt(0)" ::: "memory");
  COMPUTE(sCur)

  #undef ACC4
  #undef COMPUTE
  #undef STAGE

  // epilogue: wave-private partial write
  float* pb = part + (size_t)blockIdx.x * (HN * PSTR);
  #pragma unroll
  for (int h = 0; h < HN; ++h) {
    #pragma unroll
    for (int j = 0; j < 3; ++j) {
      float4 v = S[h][j];
      v.x += ch[h]; v.y += ch[h]; v.z += ch[h]; v.w += ch[h];
      *reinterpret_cast<float4*>(pb + h * PSTR + j * 256 + lane * 4) = v;
    }
  }
  if (lane == 0) {
    #pragma unroll
    for (int h = 0; h < HN; ++h) pb[h * PSTR + 768] = se[h];
  }
}

// ---------------- kernel 2a: combine 64 chunk partials -> xbar[b][h][768]
__global__ __launch_bounds__(256) void k_red(const float* __restrict__ part,
                                             const float* __restrict__ gamma1,
                                             const float* __restrict__ beta1,
                                             float* __restrict__ xbar) {
  int b = blockIdx.x >> 3;
  int h = blockIdx.x & 7;
  int t = threadIdx.x;
  const int CPB = LL / ROWS;   // 64 chunks per batch
  const float* pb = part + ((size_t)b * CPB * HN + h) * PSTR;
  float se = 0.f, a0 = 0.f, a1 = 0.f, a2 = 0.f;
  #pragma unroll 4
  for (int i = 0; i < CPB; ++i) {
    const float* P = pb + (size_t)i * HN * PSTR;
    se += P[768];
    a0 += P[t];
    a1 += P[t + 256];
    a2 += P[t + 512];
  }
  float inv = 1.f / se;
  size_t ob = ((size_t)b * HN + h) * DD;
  xbar[ob + t]       = fmaf(gamma1[t],       a0 * inv, beta1[t]);
  xbar[ob + t + 256] = fmaf(gamma1[t + 256], a1 * inv, beta1[t + 256]);
  xbar[ob + t + 512] = fmaf(gamma1[t + 512], a2 * inv, beta1[t + 512]);
}

// ---------------- kernel 2b: V-projection (96 blocks: 32 b x 3 g-chunks)
__global__ __launch_bounds__(256) void k_proj(
    const float* __restrict__ xbar, const float* __restrict__ wkv,
    float* __restrict__ outp) {
  int b  = blockIdx.x / 3;
  int gc = blockIdx.x % 3;
  int t  = threadIdx.x;
  __shared__ float xb[HN * DD];
  #pragma unroll
  for (int k = 0; k < 24; ++k) xb[k * 256 + t] = xbar[(size_t)b * HN * DD + k * 256 + t];
  __syncthreads();

  int g = gc * 256 + t;
  int h = g / 96;
  const float4* wrow = reinterpret_cast<const float4*>(wkv + (size_t)(DD + g) * DD);
  const float* xh = xb + h * DD;
  float acc = 0.f;
  #pragma unroll 4
  for (int e = 0; e < 192; ++e) {
    float4 w = wrow[e];
    acc = fmaf(w.x, xh[e * 4 + 0], acc);
    acc = fmaf(w.y, xh[e * 4 + 1], acc);
    acc = fmaf(w.z, xh[e * 4 + 2], acc);
    acc = fmaf(w.w, xh[e * 4 + 3], acc);
  }
  outp[(size_t)b * DD + g] = acc;
}

// ---------------- kernel 2c: final LN over 768
__global__ __launch_bounds__(768) void k_ln2(
    const float* __restrict__ outp, const float* __restrict__ gamma2,
    const float* __restrict__ beta2, float* __restrict__ out) {
  int b = blockIdx.x;
  int t = threadIdx.x;
  __shared__ float rs1[12], rs2[12];
  __shared__ float smu, srstd;
  float o = outp[(size_t)b * DD + t];
  float v1 = o, v2 = o * o;
  #pragma unroll
  for (int off = 1; off < 64; off <<= 1) {
    v1 += __shfl_xor(v1, off, 64);
    v2 += __shfl_xor(v2, off, 64);
  }
  int wv = t >> 6, ln = t & 63;
  if (ln == 0) { rs1[wv] = v1; rs2[wv] = v2; }
  __syncthreads();
  if (t == 0) {
    float s1 = 0.f, s2 = 0.f;
    #pragma unroll
    for (int w = 0; w < 12; ++w) { s1 += rs1[w]; s2 += rs2[w]; }
    float mu = s1 * (1.f / 768.f);
    float var = fmaf(-mu, mu, s2 * (1.f / 768.f));
    smu = mu;
    srstd = rsqrtf(var + 1e-5f);
  }
  __syncthreads();
  out[(size_t)b * DD + t] = fmaf((o - smu) * srstd, gamma2[t], beta2[t]);
}

extern "C" void kernel_launch(void* const* d_in, const int* in_sizes, int n_in,
                              void* d_out, int out_size, void* d_ws, size_t ws_size,
                              hipStream_t stream) {
  const float* x     = (const float*)d_in[0];
  const float* wkv   = (const float*)d_in[1];
  const float* query = (const float*)d_in[2];
  const float* g1    = (const float*)d_in[3];
  const float* b1    = (const float*)d_in[4];
  const float* g2    = (const float*)d_in[5];
  const float* b2    = (const float*)d_in[6];
  float* out = (float*)d_out;
  float* ws  = (float*)d_ws;

  float* qkraw = ws;                                   // 6144 floats (pad 8192)
  float* part  = ws + 8192;                            // NBLK*HN*PSTR (~50.6 MB)
  float* xbar  = part + (size_t)NBLK * HN * PSTR;      // BB*HN*DD
  float* outp  = xbar + (size_t)BB * HN * DD;          // BB*DD

  k_qk  <<<24,      256, 0, stream>>>(wkv, query, g1, qkraw);
  k_main<<<NBLK,    64,  0, stream>>>(x, qkraw, part);
  k_red <<<BB * HN, 256, 0, stream>>>(part, g1, b1, xbar);
  k_proj<<<BB * 3,  256, 0, stream>>>(xbar, wkv, outp);
  k_ln2 <<<BB,      768, 0, stream>>>(outp, g2, b2, out);
}

// Round 11
// 170.669 us; speedup vs baseline: 1.2616x; 1.1052x over previous
//
#include <hip/hip_runtime.h>
#include <stdint.h>

#define DD 768
#define HN 8
#define LL 4096
#define BB 32
#define ROWS 64                 // rows per 1-wave block
#define NBLK (BB * LL / ROWS)   // 2048 blocks = 8/CU x 256 CU
#define NP (ROWS / 2)           // 32 row-pairs
#define PSTR 772                // per-(block,head) partial: S[768], se at [768]

#define GLOBAL_AS __attribute__((address_space(1)))
#define LDS_AS    __attribute__((address_space(3)))

// ---- DPP wave64 sum: 6 rounds, VALU-only, 4-wide ILP ----
#define DPP_STEP(x, ctrl, rmask, bc)                                           \
  x += __int_as_float(__builtin_amdgcn_update_dpp(                             \
      0, __float_as_int(x), (ctrl), (rmask), 0xf, (bc)))

__device__ __forceinline__ void wave_sum4(float& a, float& b, float& c, float& d) {
  DPP_STEP(a, 0x111, 0xf, true);  DPP_STEP(b, 0x111, 0xf, true);
  DPP_STEP(c, 0x111, 0xf, true);  DPP_STEP(d, 0x111, 0xf, true);
  DPP_STEP(a, 0x112, 0xf, true);  DPP_STEP(b, 0x112, 0xf, true);
  DPP_STEP(c, 0x112, 0xf, true);  DPP_STEP(d, 0x112, 0xf, true);
  DPP_STEP(a, 0x114, 0xf, true);  DPP_STEP(b, 0x114, 0xf, true);
  DPP_STEP(c, 0x114, 0xf, true);  DPP_STEP(d, 0x114, 0xf, true);
  DPP_STEP(a, 0x118, 0xf, true);  DPP_STEP(b, 0x118, 0xf, true);
  DPP_STEP(c, 0x118, 0xf, true);  DPP_STEP(d, 0x118, 0xf, true);
  DPP_STEP(a, 0x142, 0xa, false); DPP_STEP(b, 0x142, 0xa, false);
  DPP_STEP(c, 0x142, 0xa, false); DPP_STEP(d, 0x142, 0xa, false);
  DPP_STEP(a, 0x143, 0xc, false); DPP_STEP(b, 0x143, 0xc, false);
  DPP_STEP(c, 0x143, 0xc, false); DPP_STEP(d, 0x143, 0xc, false);
  a = __int_as_float(__builtin_amdgcn_readlane(__float_as_int(a), 63));
  b = __int_as_float(__builtin_amdgcn_readlane(__float_as_int(b), 63));
  c = __int_as_float(__builtin_amdgcn_readlane(__float_as_int(c), 63));
  d = __int_as_float(__builtin_amdgcn_readlane(__float_as_int(d), 63));
}

// ---------------- kernel 0: RAW qk[h][d] = gamma1[d]*scale*sum_i q[h*96+i]*w[h*96+i][d]
__global__ __launch_bounds__(256) void k_qk(const float* __restrict__ wkv,
                                            const float* __restrict__ query,
                                            const float* __restrict__ gamma1,
                                            float* __restrict__ qkraw) {
  int h = blockIdx.x / 3;
  int d = (blockIdx.x % 3) * 256 + threadIdx.x;
  const float* wbase = wkv + (size_t)h * 96 * DD + d;
  const float* qb = query + h * 96;
  float acc = 0.f;
  #pragma unroll 8
  for (int i = 0; i < 96; ++i) acc = fmaf(qb[i], wbase[(size_t)i * DD], acc);
  qkraw[h * DD + d] = acc * 0.10206207261596577f * gamma1[d];
}

// ---------------- kernel 1: 1-wave blocks, 8 heads/wave, pair-iteration ring
__global__ __launch_bounds__(64, 2) void k_main(
    const float* __restrict__ x, const float* __restrict__ qkraw,
    float* __restrict__ part) {
  const int lane = threadIdx.x;          // 0..63
  __shared__ float lds[3][2][DD];        // 3 pair-slots (18 KB)
  float* ring = &lds[0][0][0];

  // q fragments for all 8 heads; center per head (softmax-shift-exact)
  float4 q[HN][3];
  #pragma unroll
  for (int h = 0; h < HN; ++h)
    #pragma unroll
    for (int j = 0; j < 3; ++j)
      q[h][j] = *reinterpret_cast<const float4*>(qkraw + h * DD + j * 256 + lane * 4);
  asm volatile("s_waitcnt vmcnt(0)" ::: "memory");  // q landed; vmcnt = stages only
  {
    float m[HN];
    #pragma unroll
    for (int h = 0; h < HN; ++h) {
      float s = 0.f;
      #pragma unroll
      for (int j = 0; j < 3; ++j)
        s += q[h][j].x + q[h][j].y + q[h][j].z + q[h][j].w;
      m[h] = s;
    }
    wave_sum4(m[0], m[1], m[2], m[3]);
    wave_sum4(m[4], m[5], m[6], m[7]);
    #pragma unroll
    for (int h = 0; h < HN; ++h) {
      float mv = m[h] * (1.f / 768.f);
      #pragma unroll
      for (int j = 0; j < 3; ++j) {
        q[h][j].x -= mv; q[h][j].y -= mv; q[h][j].z -= mv; q[h][j].w -= mv;
      }
    }
  }

  float4 S[HN][3];
  float se[HN], ch[HN];
  #pragma unroll
  for (int h = 0; h < HN; ++h) {
    se[h] = 0.f; ch[h] = 0.f;
    #pragma unroll
    for (int j = 0; j < 3; ++j) S[h][j] = make_float4(0.f, 0.f, 0.f, 0.f);
  }

  const float* gbase = x + (size_t)blockIdx.x * ROWS * DD;

  // stage pair P into pair-slot SLOT: 6x 16B DMA (6 vmcnt events)
  #define STAGEP(P, SLOT)                                                      \
    {                                                                          \
      const float* gt = gbase + (size_t)(P) * (2 * DD);                        \
      float* db = ring + (SLOT) * (2 * DD);                                    \
      _Pragma("unroll")                                                        \
      for (int i = 0; i < 6; ++i)                                              \
        __builtin_amdgcn_global_load_lds(                                      \
            (const GLOBAL_AS uint32_t*)(gt + i * 256 + lane * 4),              \
            (LDS_AS uint32_t*)(db + i * 256), 16, 0, 0);                       \
    }

#define ACC4(cv, J, DT)                                                        \
      s1 += cv.x + cv.y + cv.z + cv.w;                                         \
      s2 = fmaf(cv.x, cv.x, s2); s2 = fmaf(cv.y, cv.y, s2);                    \
      s2 = fmaf(cv.z, cv.z, s2); s2 = fmaf(cv.w, cv.w, s2);                    \
      _Pragma("unroll")                                                        \
      for (int h = 0; h < HN; ++h) {                                           \
        DT[h] = fmaf(cv.x, q[h][J].x, DT[h]);                                  \
        DT[h] = fmaf(cv.y, q[h][J].y, DT[h]);                                  \
        DT[h] = fmaf(cv.z, q[h][J].z, DT[h]);                                  \
        DT[h] = fmaf(cv.w, q[h][J].w, DT[h]);                                  \
      }

  #define TAIL(S1, S2, DT, C0, C1, C2)                                         \
    {                                                                          \
      float mu   = S1 * (1.f / 768.f);                                         \
      float var  = fmaf(-mu, mu, S2 * (1.f / 768.f));                          \
      float rstd = rsqrtf(var + 1e-5f);                                        \
      float sh   = -mu * rstd;                                                 \
      float pe   = rstd * 1.44269504f;                                         \
      _Pragma("unroll")                                                        \
      for (int h = 0; h < HN; ++h) {                                           \
        float p = exp2f(DT[h] * pe);                                           \
        se[h] += p;                                                            \
        ch[h] = fmaf(p, sh, ch[h]);                                            \
        float a = p * rstd;                                                    \
        S[h][0].x = fmaf(a, C0.x, S[h][0].x);                                  \
        S[h][0].y = fmaf(a, C0.y, S[h][0].y);                                  \
        S[h][0].z = fmaf(a, C0.z, S[h][0].z);                                  \
        S[h][0].w = fmaf(a, C0.w, S[h][0].w);                                  \
        S[h][1].x = fmaf(a, C1.x, S[h][1].x);                                  \
        S[h][1].y = fmaf(a, C1.y, S[h][1].y);                                  \
        S[h][1].z = fmaf(a, C1.z, S[h][1].z);                                  \
        S[h][1].w = fmaf(a, C1.w, S[h][1].w);                                  \
        S[h][2].x = fmaf(a, C2.x, S[h][2].x);                                  \
        S[h][2].y = fmaf(a, C2.y, S[h][2].y);                                  \
        S[h][2].z = fmaf(a, C2.z, S[h][2].z);                                  \
        S[h][2].w = fmaf(a, C2.w, S[h][2].w);                                  \
      }                                                                        \
    }

  // compute pair at SLOT: 6 ds_reads up front, both rows' chains interleavable
  #define COMPUTEP(SLOT)                                                       \
    {                                                                          \
      const float* ra = ring + (SLOT) * (2 * DD);                              \
      float4 a0 = *reinterpret_cast<const float4*>(ra + lane * 4);             \
      float4 a1 = *reinterpret_cast<const float4*>(ra + 256 + lane * 4);       \
      float4 a2 = *reinterpret_cast<const float4*>(ra + 512 + lane * 4);       \
      float4 b0 = *reinterpret_cast<const float4*>(ra + 768 + lane * 4);       \
      float4 b1 = *reinterpret_cast<const float4*>(ra + 1024 + lane * 4);      \
      float4 b2 = *reinterpret_cast<const float4*>(ra + 1280 + lane * 4);      \
      float dta[HN], dtb[HN];                                                  \
      _Pragma("unroll") for (int h = 0; h < HN; ++h) { dta[h] = 0.f; dtb[h] = 0.f; } \
      float s1a, s2a, s1b, s2b;                                                \
      { float s1 = 0.f, s2 = 0.f;                                              \
        ACC4(a0, 0, dta) ACC4(a1, 1, dta) ACC4(a2, 2, dta)                     \
        s1a = s1; s2a = s2; }                                                  \
      { float s1 = 0.f, s2 = 0.f;                                              \
        ACC4(b0, 0, dtb) ACC4(b1, 1, dtb) ACC4(b2, 2, dtb)                     \
        s1b = s1; s2b = s2; }                                                  \
      wave_sum4(s1a, s2a, s1b, s2b);                                           \
      wave_sum4(dta[0], dta[1], dta[2], dta[3]);                               \
      wave_sum4(dta[4], dta[5], dta[6], dta[7]);                               \
      wave_sum4(dtb[0], dtb[1], dtb[2], dtb[3]);                               \
      wave_sum4(dtb[4], dtb[5], dtb[6], dtb[7]);                               \
      TAIL(s1a, s2a, dta, a0, a1, a2)                                          \
      TAIL(s1b, s2b, dtb, b0, b1, b2)                                          \
    }

  // prologue: 3 pairs in flight (18 loads) into slots 0,1,2
  STAGEP(0, 0) STAGEP(1, 1) STAGEP(2, 2)

  int slot = 0;
  #pragma unroll 1
  for (int p = 0; p <= NP - 3; ++p) {
    asm volatile("s_waitcnt vmcnt(12)" ::: "memory");  // pair p landed
    COMPUTEP(slot)
    if (p + 3 < NP) STAGEP(p + 3, slot)                // reuse pair p's slot
    slot = (slot == 2) ? 0 : slot + 1;
  }
  asm volatile("s_waitcnt vmcnt(6)" ::: "memory");
  COMPUTEP(slot)
  slot = (slot == 2) ? 0 : slot + 1;
  asm volatile("s_waitcnt vmcnt(0)" ::: "memory");
  COMPUTEP(slot)

  #undef COMPUTEP
  #undef TAIL
  #undef ACC4
  #undef STAGEP

  // epilogue: wave-private partial write
  float* pb = part + (size_t)blockIdx.x * (HN * PSTR);
  #pragma unroll
  for (int h = 0; h < HN; ++h) {
    #pragma unroll
    for (int j = 0; j < 3; ++j) {
      float4 v = S[h][j];
      v.x += ch[h]; v.y += ch[h]; v.z += ch[h]; v.w += ch[h];
      *reinterpret_cast<float4*>(pb + h * PSTR + j * 256 + lane * 4) = v;
    }
  }
  if (lane == 0) {
    #pragma unroll
    for (int h = 0; h < HN; ++h) pb[h * PSTR + 768] = se[h];
  }
}

// ---------------- kernel 2a: combine 64 chunk partials -> xbar[b][h][768]
__global__ __launch_bounds__(256) void k_red(const float* __restrict__ part,
                                             const float* __restrict__ gamma1,
                                             const float* __restrict__ beta1,
                                             float* __restrict__ xbar) {
  int b = blockIdx.x >> 3;
  int h = blockIdx.x & 7;
  int t = threadIdx.x;
  const int CPB = LL / ROWS;   // 64 chunks per batch
  const float* pb = part + ((size_t)b * CPB * HN + h) * PSTR;
  float se = 0.f, a0 = 0.f, a1 = 0.f, a2 = 0.f;
  #pragma unroll 4
  for (int i = 0; i < CPB; ++i) {
    const float* P = pb + (size_t)i * HN * PSTR;
    se += P[768];
    a0 += P[t];
    a1 += P[t + 256];
    a2 += P[t + 512];
  }
  float inv = 1.f / se;
  size_t ob = ((size_t)b * HN + h) * DD;
  xbar[ob + t]       = fmaf(gamma1[t],       a0 * inv, beta1[t]);
  xbar[ob + t + 256] = fmaf(gamma1[t + 256], a1 * inv, beta1[t + 256]);
  xbar[ob + t + 512] = fmaf(gamma1[t + 512], a2 * inv, beta1[t + 512]);
}

// ---------------- kernel 2b: V-projection (96 blocks: 32 b x 3 g-chunks)
__global__ __launch_bounds__(256) void k_proj(
    const float* __restrict__ xbar, const float* __restrict__ wkv,
    float* __restrict__ outp) {
  int b  = blockIdx.x / 3;
  int gc = blockIdx.x % 3;
  int t  = threadIdx.x;
  __shared__ float xb[HN * DD];
  #pragma unroll
  for (int k = 0; k < 24; ++k) xb[k * 256 + t] = xbar[(size_t)b * HN * DD + k * 256 + t];
  __syncthreads();

  int g = gc * 256 + t;
  int h = g / 96;
  const float4* wrow = reinterpret_cast<const float4*>(wkv + (size_t)(DD + g) * DD);
  const float* xh = xb + h * DD;
  float acc = 0.f;
  #pragma unroll 4
  for (int e = 0; e < 192; ++e) {
    float4 w = wrow[e];
    acc = fmaf(w.x, xh[e * 4 + 0], acc);
    acc = fmaf(w.y, xh[e * 4 + 1], acc);
    acc = fmaf(w.z, xh[e * 4 + 2], acc);
    acc = fmaf(w.w, xh[e * 4 + 3], acc);
  }
  outp[(size_t)b * DD + g] = acc;
}

// ---------------- kernel 2c: final LN over 768
__global__ __launch_bounds__(768) void k_ln2(
    const float* __restrict__ outp, const float* __restrict__ gamma2,
    const float* __restrict__ beta2, float* __restrict__ out) {
  int b = blockIdx.x;
  int t = threadIdx.x;
  __shared__ float rs1[12], rs2[12];
  __shared__ float smu, srstd;
  float o = outp[(size_t)b * DD + t];
  float v1 = o, v2 = o * o;
  #pragma unroll
  for (int off = 1; off < 64; off <<= 1) {
    v1 += __shfl_xor(v1, off, 64);
    v2 += __shfl_xor(v2, off, 64);
  }
  int wv = t >> 6, ln = t & 63;
  if (ln == 0) { rs1[wv] = v1; rs2[wv] = v2; }
  __syncthreads();
  if (t == 0) {
    float s1 = 0.f, s2 = 0.f;
    #pragma unroll
    for (int w = 0; w < 12; ++w) { s1 += rs1[w]; s2 += rs2[w]; }
    float mu = s1 * (1.f / 768.f);
    float var = fmaf(-mu, mu, s2 * (1.f / 768.f));
    smu = mu;
    srstd = rsqrtf(var + 1e-5f);
  }
  __syncthreads();
  out[(size_t)b * DD + t] = fmaf((o - smu) * srstd, gamma2[t], beta2[t]);
}

extern "C" void kernel_launch(void* const* d_in, const int* in_sizes, int n_in,
                              void* d_out, int out_size, void* d_ws, size_t ws_size,
                              hipStream_t stream) {
  const float* x     = (const float*)d_in[0];
  const float* wkv   = (const float*)d_in[1];
  const float* query = (const float*)d_in[2];
  const float* g1    = (const float*)d_in[3];
  const float* b1    = (const float*)d_in[4];
  const float* g2    = (const float*)d_in[5];
  const float* b2    = (const float*)d_in[6];
  float* out = (float*)d_out;
  float* ws  = (float*)d_ws;

  float* qkraw = ws;                                   // 6144 floats (pad 8192)
  float* part  = ws + 8192;                            // NBLK*HN*PSTR (~50.6 MB)
  float* xbar  = part + (size_t)NBLK * HN * PSTR;      // BB*HN*DD
  float* outp  = xbar + (size_t)BB * HN * DD;          // BB*DD

  k_qk  <<<24,      256, 0, stream>>>(wkv, query, g1, qkraw);
  k_main<<<NBLK,    64,  0, stream>>>(x, qkraw, part);
  k_red <<<BB * HN, 256, 0, stream>>>(part, g1, b1, xbar);
  k_proj<<<BB * 3,  256, 0, stream>>>(xbar, wkv, outp);
  k_ln2 <<<BB,      768, 0, stream>>>(outp, g2, b2, out);
}